// Round 5
// baseline (1211.864 us; speedup 1.0000x reference)
//
#include <hip/hip_runtime.h>

typedef float f32x2 __attribute__((ext_vector_type(2)));

#define A2B 512   // edge chunks (A1 histogram / A2 bucket blocks)
#define A2T 512   // threads in A2
#define STG 3200  // staged records per chunk (>= ceil(E/A2B))
// NOTE: edge records are packed as (src | dst<<16, w) -- requires n <= 65536.
// NOTE: h is stored as fp8 e4m3 (HW cvt, RNE) -- 3.2 MB, per-XCD L2-resident.
// NOTE: aggregation is bucket-blocked LDS scatter-accumulate: one block per
//       256-row bucket holds acc[dwidth][65] f32 in LDS and streams the
//       bucket's records (ds_add_f32). No CSR build, no edges array, no
//       rowptr -- k_build/k_place deleted. Global atomics are NEVER used
//       (round-4 lesson: memory-side atomics cost 32B HBM tx each).

// ---------- helpers ----------
__device__ __forceinline__ long ld_idx(const void* idx, long pos, int is64) {
  return is64 ? (long)((const long long*)idx)[pos]
              : (long)((const int*)idx)[pos];
}

// Per-wave dtype detection: true int64 indices are all < 2^32.
__device__ __forceinline__ int detect_is64(const void* idx) {
  const unsigned long long* p = (const unsigned long long*)idx;
  unsigned long long v = p[threadIdx.x & 63];
  return (__ballot((v >> 32) != 0ull) == 0ull) ? 1 : 0;
}

// ---------- fp8 pack helper: 16 fp32 -> 16 e4m3 bytes (uint4) ----------
__device__ __forceinline__ uint4 pack16_fp8(const float* acc) {
  uint4 o;
  unsigned v;
  v = 0;
  v = __builtin_amdgcn_cvt_pk_fp8_f32(acc[0],  acc[1],  v, false);
  v = __builtin_amdgcn_cvt_pk_fp8_f32(acc[2],  acc[3],  v, true);
  o.x = v; v = 0;
  v = __builtin_amdgcn_cvt_pk_fp8_f32(acc[4],  acc[5],  v, false);
  v = __builtin_amdgcn_cvt_pk_fp8_f32(acc[6],  acc[7],  v, true);
  o.y = v; v = 0;
  v = __builtin_amdgcn_cvt_pk_fp8_f32(acc[8],  acc[9],  v, false);
  v = __builtin_amdgcn_cvt_pk_fp8_f32(acc[10], acc[11], v, true);
  o.z = v; v = 0;
  v = __builtin_amdgcn_cvt_pk_fp8_f32(acc[12], acc[13], v, false);
  v = __builtin_amdgcn_cvt_pk_fp8_f32(acc[14], acc[15], v, true);
  o.w = v;
  return o;
}

// unpack 8 fp8 bytes (uint2) -> 8 floats
__device__ __forceinline__ void fp8x8_to_f32(uint2 hv, float* p) {
  f32x2 p0 = __builtin_amdgcn_cvt_pk_f32_fp8(hv.x, false);
  f32x2 p1 = __builtin_amdgcn_cvt_pk_f32_fp8(hv.x, true);
  f32x2 p2 = __builtin_amdgcn_cvt_pk_f32_fp8(hv.y, false);
  f32x2 p3 = __builtin_amdgcn_cvt_pk_f32_fp8(hv.y, true);
  p[0] = p0[0]; p[1] = p0[1]; p[2] = p1[0]; p[3] = p1[1];
  p[4] = p2[0]; p[5] = p2[1]; p[6] = p3[0]; p[7] = p3[1];
}

// ---------- FRONT: blocks [0,A2B) = per-chunk 256-bucket histogram;
//                   blocks [A2B,..) = gemm1 (4 threads/node, W1 in LDS) ----------
__global__ __launch_bounds__(256) void k_front(const void* __restrict__ idx,
                                               unsigned* __restrict__ histT,
                                               long E, int chunk, unsigned M,
                                               const float* __restrict__ X,
                                               const float* __restrict__ W1,
                                               unsigned char* __restrict__ h, int n) {
  __shared__ float smem[2048];   // hist uses 1 KB as uint; gemm1 uses 8 KB as W tile
  const int t = threadIdx.x;
  if (blockIdx.x < A2B) {
    unsigned* cnt = (unsigned*)smem;
    const int b = blockIdx.x;
    const int is64 = detect_is64(idx);
    cnt[t] = 0;
    __syncthreads();
    const long e0 = (long)b * chunk;
    long e1 = e0 + chunk; if (e1 > E) e1 = E;
    for (long e = e0 + t; e < e1; e += 256) {
      unsigned d = (unsigned)ld_idx(idx, E + e, is64);
      atomicAdd(&cnt[__umulhi(d, M)], 1u);
    }
    __syncthreads();
    histT[(size_t)t * A2B + b] = cnt[t];   // k-major
    return;
  }
  // ----- gemm1 -----
  float* Ws = smem;
  for (int i = t; i < 2048; i += 256)
    ((float4*)Ws)[i] = ((const float4*)W1)[i];
  __syncthreads();
  int gid = (blockIdx.x - A2B) * 256 + t;
  int node = gid >> 2;
  int fg = (gid & 3) * 16;
  if (node >= n) return;
  const float4* xr4 = (const float4*)(X + (size_t)node * 128);
  float acc[16];
#pragma unroll
  for (int f = 0; f < 16; ++f) acc[f] = 0.0f;
  for (int k4 = 0; k4 < 32; ++k4) {
    float4 x = xr4[k4];
#pragma unroll
    for (int kk = 0; kk < 4; ++kk) {
      float xv = (kk == 0) ? x.x : (kk == 1) ? x.y : (kk == 2) ? x.z : x.w;
      const float4* wrow = (const float4*)(Ws + (k4 * 4 + kk) * 64 + fg);
#pragma unroll
      for (int f4 = 0; f4 < 4; ++f4) {
        float4 w = wrow[f4];
        acc[f4 * 4 + 0] = fmaf(xv, w.x, acc[f4 * 4 + 0]);
        acc[f4 * 4 + 1] = fmaf(xv, w.y, acc[f4 * 4 + 1]);
        acc[f4 * 4 + 2] = fmaf(xv, w.z, acc[f4 * 4 + 2]);
        acc[f4 * 4 + 3] = fmaf(xv, w.w, acc[f4 * 4 + 3]);
      }
    }
  }
  *(uint4*)(h + (size_t)node * 64 + fg) = pack16_fp8(acc);
}

// ---------- C1: per-bucket column scan (256 blocks, coalesced) ----------
__global__ __launch_bounds__(256) void k_colscan(const unsigned* __restrict__ histT,
                                                 unsigned* __restrict__ baseT,
                                                 unsigned* __restrict__ colsum) {
  __shared__ unsigned sh[256];
  const int k = blockIdx.x, t = threadIdx.x;
  const uint2 v = ((const uint2*)(histT + (size_t)k * A2B))[t];
  unsigned s = v.x + v.y;
  sh[t] = s;
  __syncthreads();
  for (int off = 1; off < 256; off <<= 1) {
    unsigned u = (t >= off) ? sh[t - off] : 0;
    __syncthreads();
    sh[t] += u;
    __syncthreads();
  }
  unsigned excl = sh[t] - s;
  uint2 o; o.x = excl; o.y = excl + v.x;
  ((uint2*)(baseT + (size_t)k * A2B))[t] = o;
  if (t == 255) colsum[k] = sh[255];
}

// ---------- A2: LDS counting-sort each chunk by bucket, write bucket-major packed recs ----------
__global__ __launch_bounds__(A2T) void k_bucket(const void* __restrict__ idx,
                                                const float* __restrict__ w,
                                                const unsigned* __restrict__ baseT,
                                                const unsigned* __restrict__ colsum,
                                                uint2* __restrict__ recs,
                                                long E, int chunk, unsigned M) {
  __shared__ uint2 stage[STG];                      // 25.6 KB
  __shared__ unsigned cnt[256], lofs[256], lbase[256], bcol[256], scanb[256];
  const int b = blockIdx.x, t = threadIdx.x;
  const long e0 = (long)b * chunk;
  long e1 = e0 + chunk; if (e1 > E) e1 = E;
  const int m = (int)(e1 - e0);
  const int is64 = detect_is64(idx);
  if (t < 256) scanb[t] = colsum[t];
  __syncthreads();
  for (int off = 1; off < 256; off <<= 1) {
    unsigned u = 0;
    if (t < 256 && t >= off) u = scanb[t - off];
    __syncthreads();
    if (t < 256) scanb[t] += u;
    __syncthreads();
  }
  if (t < 256) {
    bcol[t] = (scanb[t] - colsum[t]) + baseT[(size_t)t * A2B + b];
    cnt[t] = 0;
  }
  __syncthreads();
  unsigned short dc[8]; unsigned char kc[8];
  int nk = 0;
  for (long e = e0 + t; e < e1; e += A2T, ++nk) {
    unsigned d = (unsigned)ld_idx(idx, E + e, is64);
    unsigned kb = __umulhi(d, M);
    dc[nk] = (unsigned short)d; kc[nk] = (unsigned char)kb;
    atomicAdd(&cnt[kb], 1u);
  }
  __syncthreads();
  if (t < 256) scanb[t] = cnt[t];
  __syncthreads();
  for (int off = 1; off < 256; off <<= 1) {
    unsigned u = 0;
    if (t < 256 && t >= off) u = scanb[t - off];
    __syncthreads();
    if (t < 256) scanb[t] += u;
    __syncthreads();
  }
  if (t < 256) { unsigned ex = scanb[t] - cnt[t]; lbase[t] = ex; lofs[t] = ex; }
  __syncthreads();
  nk = 0;
  for (long e = e0 + t; e < e1; e += A2T, ++nk) {
    unsigned s = (unsigned)ld_idx(idx, e, is64);
    float wv = w[e];
    unsigned kb = kc[nk];
    unsigned pos = atomicAdd(&lofs[kb], 1u);
    stage[pos] = make_uint2(s | ((unsigned)dc[nk] << 16), __float_as_uint(wv));
  }
  __syncthreads();
  for (int i = t; i < m; i += A2T) {
    uint2 r = stage[i];
    unsigned kb = __umulhi(r.x >> 16, M);
    recs[bcol[kb] + (unsigned)i - lbase[kb]] = r;
  }
}

// ---------- DIS: one block per bucket; wsum via LDS float atomics -> dis ----------
__global__ __launch_bounds__(1024) void k_dis(const uint2* __restrict__ recs,
                                              const unsigned* __restrict__ colsum,
                                              float* __restrict__ dis,
                                              int n, int dwidth) {
  __shared__ float wsum[256];
  __shared__ unsigned scanb[256];
  __shared__ int shr0, shr1;
  const int k = blockIdx.x, t = threadIdx.x;
  const int d0 = k * dwidth;
  if (t < 256) { scanb[t] = colsum[t]; wsum[t] = 0.0f; }
  __syncthreads();
  for (int off = 1; off < 256; off <<= 1) {
    unsigned u = 0;
    if (t < 256 && t >= off) u = scanb[t - off];
    __syncthreads();
    if (t < 256) scanb[t] += u;
    __syncthreads();
  }
  if (t == k) { shr1 = (int)scanb[t]; shr0 = (int)(scanb[t] - colsum[t]); }
  __syncthreads();
  const int r0 = shr0, r1 = shr1;
  for (int i = r0 + t; i < r1; i += 1024) {
    uint2 r = recs[i];
    atomicAdd(&wsum[(int)(r.x >> 16) - d0], __uint_as_float(r.y));
  }
  __syncthreads();
  if (t < 256) {
    int d = d0 + t;
    if (t < dwidth && d < n) dis[d] = rsqrtf(1.0f + wsum[t]);  // self-loop wt 1
  }
}

// ---------- GMID: bucket-blocked scatter-acc of layer-1 + fused gemm2 -> h2 ----------
// LDS: acc[dwidth][65] f32 (dynamic, pad-65 kills bank conflicts) + W2 tile.
__global__ __launch_bounds__(1024) void k_gmid(const uint2* __restrict__ recs,
                                               const unsigned* __restrict__ colsum,
                                               const unsigned char* __restrict__ h,
                                               const float* __restrict__ dis,
                                               const float* __restrict__ b1,
                                               const float* __restrict__ W2,
                                               unsigned char* __restrict__ h2,
                                               int n, int dwidth) {
  __shared__ float W2s[4096];     // 16 KB
  __shared__ float b1l[64];
  __shared__ float disl[256];
  __shared__ unsigned scanb[256];
  __shared__ int shr0, shr1;
  extern __shared__ float accp[]; // dwidth * 65 floats
  const int k = blockIdx.x, t = threadIdx.x;
  const int d0 = k * dwidth;
  if (t < 256) scanb[t] = colsum[t];
  __syncthreads();
  for (int off = 1; off < 256; off <<= 1) {
    unsigned u = 0;
    if (t < 256 && t >= off) u = scanb[t - off];
    __syncthreads();
    if (t < 256) scanb[t] += u;
    __syncthreads();
  }
  if (t == k) { shr1 = (int)scanb[t]; shr0 = (int)(scanb[t] - colsum[t]); }
  ((float4*)W2s)[t] = ((const float4*)W2)[t];          // 1024 float4 = whole W2
  if (t < 64) b1l[t] = b1[t];
  if (t < 256) {
    int d = d0 + t;
    disl[t] = (t < dwidth && d < n) ? dis[d] : 0.0f;
  }
  const int na = dwidth * 65;
  for (int i = t; i < na; i += 1024) accp[i] = 0.0f;
  __syncthreads();
  const int r0 = shr0, r1 = shr1;
  // ---- scatter-accumulate: 128 recs per iteration, 8 feature-lanes/rec ----
  const int fl = t & 7, rid = t >> 3;
  for (int ri = r0 + rid; ri < r1; ri += 128) {
    uint2 rec = recs[ri];
    int src = (int)(rec.x & 0xffffu);
    int dl = (int)(rec.x >> 16) - d0;
    float nrm = __uint_as_float(rec.y) * dis[src];
    uint2 hv = *(const uint2*)(h + (size_t)src * 64 + fl * 8);
    float p[8];
    fp8x8_to_f32(hv, p);
    float* ap = accp + dl * 65 + fl * 8;
#pragma unroll
    for (int i = 0; i < 8; ++i) atomicAdd(ap + i, p[i] * nrm);
  }
  __syncthreads();
  // ---- x = relu(acc*s0 + b1 + self*s0^2), in place ----
  for (int g = t; g < dwidth * 8; g += 1024) {
    int r = g >> 3, f8 = (g & 7) * 8;
    int node = d0 + r;
    if (node >= n) continue;
    float s0 = disl[r], s2 = s0 * s0;
    uint2 hv = *(const uint2*)(h + (size_t)node * 64 + f8);
    float hs[8];
    fp8x8_to_f32(hv, hs);
    float* ap = accp + r * 65 + f8;
#pragma unroll
    for (int i = 0; i < 8; ++i)
      ap[i] = fmaxf(fmaf(ap[i], s0, fmaf(hs[i], s2, b1l[f8 + i])), 0.0f);
  }
  __syncthreads();
  // ---- gemm2: 32 threads/row, 2 outputs each ----
  const int rg = t >> 5, tl = t & 31, f = tl * 2;
  for (int r = rg; r < dwidth; r += 32) {
    int node = d0 + r;
    if (node >= n) continue;
    const float* xr = accp + r * 65;
    float a0 = 0.0f, a1 = 0.0f;
#pragma unroll 8
    for (int kk = 0; kk < 64; ++kk) {
      float xk = xr[kk];
      f32x2 wv = *(const f32x2*)(W2s + kk * 64 + f);
      a0 = fmaf(xk, wv[0], a0);
      a1 = fmaf(xk, wv[1], a1);
    }
    unsigned v = __builtin_amdgcn_cvt_pk_fp8_f32(a0, a1, 0u, false);
    *(unsigned short*)(h2 + (size_t)node * 64 + f) = (unsigned short)v;
  }
}

// ---------- GFIN: bucket-blocked scatter-acc of layer-2 + fused readout ----------
__global__ __launch_bounds__(1024) void k_gfin(const uint2* __restrict__ recs,
                                               const unsigned* __restrict__ colsum,
                                               const unsigned char* __restrict__ h,
                                               const float* __restrict__ dis,
                                               const float* __restrict__ b2,
                                               const float* __restrict__ Wl,
                                               const float* __restrict__ bl,
                                               float* __restrict__ out,
                                               int n, int dwidth) {
  __shared__ float b2l[64], Wll[64];
  __shared__ float disl[256];
  __shared__ unsigned scanb[256];
  __shared__ int shr0, shr1;
  extern __shared__ float accp[]; // dwidth * 65 floats
  const int k = blockIdx.x, t = threadIdx.x;
  const int d0 = k * dwidth;
  if (t < 256) scanb[t] = colsum[t];
  __syncthreads();
  for (int off = 1; off < 256; off <<= 1) {
    unsigned u = 0;
    if (t < 256 && t >= off) u = scanb[t - off];
    __syncthreads();
    if (t < 256) scanb[t] += u;
    __syncthreads();
  }
  if (t == k) { shr1 = (int)scanb[t]; shr0 = (int)(scanb[t] - colsum[t]); }
  if (t < 64) { b2l[t] = b2[t]; Wll[t] = Wl[t]; }
  if (t < 256) {
    int d = d0 + t;
    disl[t] = (t < dwidth && d < n) ? dis[d] : 0.0f;
  }
  const int na = dwidth * 65;
  for (int i = t; i < na; i += 1024) accp[i] = 0.0f;
  __syncthreads();
  const int r0 = shr0, r1 = shr1;
  const int fl = t & 7, rid = t >> 3;
  for (int ri = r0 + rid; ri < r1; ri += 128) {
    uint2 rec = recs[ri];
    int src = (int)(rec.x & 0xffffu);
    int dl = (int)(rec.x >> 16) - d0;
    float nrm = __uint_as_float(rec.y) * dis[src];
    uint2 hv = *(const uint2*)(h + (size_t)src * 64 + fl * 8);
    float p[8];
    fp8x8_to_f32(hv, p);
    float* ap = accp + dl * 65 + fl * 8;
#pragma unroll
    for (int i = 0; i < 8; ++i) atomicAdd(ap + i, p[i] * nrm);
  }
  __syncthreads();
  // ---- fused epilogue + readout: 8 lanes/row, shfl-reduce ----
  for (int r = rid; r < dwidth; r += 128) {
    int node = d0 + r;
    if (node >= n) continue;
    float s0 = disl[r], s2 = s0 * s0;
    uint2 hv = *(const uint2*)(h + (size_t)node * 64 + fl * 8);
    float hs[8];
    fp8x8_to_f32(hv, hs);
    const float* ap = accp + r * 65 + fl * 8;
    float v = 0.0f;
#pragma unroll
    for (int i = 0; i < 8; ++i) {
      float x = fmaxf(fmaf(ap[i], s0, fmaf(hs[i], s2, b2l[fl * 8 + i])), 0.0f);
      v += x * Wll[fl * 8 + i];
    }
    v += __shfl_xor(v, 1);
    v += __shfl_xor(v, 2);
    v += __shfl_xor(v, 4);
    if (fl == 0) out[node] = 1.0f / (1.0f + expf(-(v + bl[0])));
  }
}

extern "C" void kernel_launch(void* const* d_in, const int* in_sizes, int n_in,
                              void* d_out, int out_size, void* d_ws, size_t ws_size,
                              hipStream_t stream) {
  const float* X  = (const float*)d_in[0];
  const void*  EI = d_in[1];
  const float* EW = (const float*)d_in[2];
  const float* W1 = (const float*)d_in[3];
  const float* b1 = (const float*)d_in[4];
  const float* W2 = (const float*)d_in[5];
  const float* b2 = (const float*)d_in[6];
  const float* Wl = (const float*)d_in[7];
  const float* bl = (const float*)d_in[8];
  float* out = (float*)d_out;

  const int  n = in_sizes[0] / 128;      // 50000 (must be <= 65536 for packed recs)
  const long E = (long)in_sizes[1] / 2;  // 1,600,000

  const int chunk  = (int)((E + A2B - 1) / A2B);       // 3125 (<= STG)
  const int dwidth = (n + 255) / 256;                  // 196  (<= 256)
  const unsigned M = (unsigned)((0x100000000ULL + (unsigned)dwidth - 1) / (unsigned)dwidth);

  auto align = [](size_t x) { return (x + 255) & ~(size_t)255; };
  char* ws = (char*)d_ws;
  size_t off = 0;
  float*         dis    = (float*)(ws + off);         off += align((size_t)n * 4);
  unsigned*      colsum = (unsigned*)(ws + off);      off += align(256 * 4);
  unsigned*      histT  = (unsigned*)(ws + off);      off += align((size_t)A2B * 256 * 4);
  unsigned*      baseT  = (unsigned*)(ws + off);      off += align((size_t)A2B * 256 * 4);
  uint2*         recs   = (uint2*)(ws + off);         off += align((size_t)E * 8);
  unsigned char* A      = (unsigned char*)(ws + off); off += align((size_t)n * 64);
  unsigned char* A2     = (unsigned char*)(ws + off); off += align((size_t)n * 64);

  const int nbG = (n * 4 + 255) / 256;        // gemm1 blocks (4 threads/node)
  const size_t ldsAcc = (size_t)dwidth * 65 * sizeof(float);  // 51 KB @ n=50000

  k_front<<<A2B + nbG, dim3(256), 0, stream>>>(EI, histT, E, chunk, M, X, W1, A, n);
  k_colscan<<<256, 256, 0, stream>>>(histT, baseT, colsum);
  k_bucket<<<A2B, A2T, 0, stream>>>(EI, EW, baseT, colsum, recs, E, chunk, M);
  k_dis<<<256, dim3(1024), 0, stream>>>(recs, colsum, dis, n, dwidth);

  // layer 1 scatter-acc + fused gemm2 -> A2 (fp8)
  k_gmid<<<256, dim3(1024), ldsAcc, stream>>>(recs, colsum, A, dis, b1, W2, A2, n, dwidth);
  // layer 2 scatter-acc + fused readout
  k_gfin<<<256, dim3(1024), ldsAcc, stream>>>(recs, colsum, A2, dis, b2, Wl, bl, out, n, dwidth);
}

// Round 6
// 208.218 us; speedup vs baseline: 5.8202x; 5.8202x over previous
//
#include <hip/hip_runtime.h>

typedef float f32x2 __attribute__((ext_vector_type(2)));

#define A2B 512   // edge chunks (A1 histogram / A2 bucket blocks)
#define A2T 512   // threads in A2
#define STG 3200  // staged records per chunk (>= ceil(E/A2B))
// NOTE: edge records are packed as (src | dst<<16, w) -- requires n <= 65536.
// NOTE: h is stored as fp8 e4m3 (HW cvt, RNE) -- 3.2 MB, per-XCD L2-resident.
// NOTE: k_place folds dis[src] into the stored edge weight at CSR-scatter time.
// NOTE: dwidth is rounded to a multiple of 8 so gather blocks can be swizzled
//       to the XCD class ((bucket)%8) that wrote their bucket's edge rows
//       (k_build/k_place block k -> XCD k%8 by round-robin heuristic).
// NOTE: NO contended float atomics anywhere (global: 32B HBM tx each, r4;
//       LDS: ~88cy/instr CAS-like serialization, r5).

// ---------- helpers ----------
__device__ __forceinline__ long ld_idx(const void* idx, long pos, int is64) {
  return is64 ? (long)((const long long*)idx)[pos]
              : (long)((const int*)idx)[pos];
}

// Per-wave dtype detection: true int64 indices are all < 2^32.
__device__ __forceinline__ int detect_is64(const void* idx) {
  const unsigned long long* p = (const unsigned long long*)idx;
  unsigned long long v = p[threadIdx.x & 63];
  return (__ballot((v >> 32) != 0ull) == 0ull) ? 1 : 0;
}

// XCD-affinity swizzle: block bid (grid = 32*dwidth) -> node-group g such that
// the owning bucket k = g/GP satisfies k%8 == bid%8 (same XCD class as the
// k_build/k_place block that wrote the bucket's edges). Bijective.
__device__ __forceinline__ int swz_group(int bid, int GP) {
  int r = bid & 7, q = bid >> 3;
  int j = q / GP;              // 0..31  (bucket within class)
  int i = q - j * GP;          // 0..GP-1 (group within bucket)
  return (r + 8 * j) * GP + i;
}

// ---------- fp8 pack helper: 16 fp32 -> 16 e4m3 bytes (uint4) ----------
__device__ __forceinline__ uint4 pack16_fp8(const float* acc) {
  uint4 o;
  unsigned v;
  v = 0;
  v = __builtin_amdgcn_cvt_pk_fp8_f32(acc[0],  acc[1],  v, false);
  v = __builtin_amdgcn_cvt_pk_fp8_f32(acc[2],  acc[3],  v, true);
  o.x = v; v = 0;
  v = __builtin_amdgcn_cvt_pk_fp8_f32(acc[4],  acc[5],  v, false);
  v = __builtin_amdgcn_cvt_pk_fp8_f32(acc[6],  acc[7],  v, true);
  o.y = v; v = 0;
  v = __builtin_amdgcn_cvt_pk_fp8_f32(acc[8],  acc[9],  v, false);
  v = __builtin_amdgcn_cvt_pk_fp8_f32(acc[10], acc[11], v, true);
  o.z = v; v = 0;
  v = __builtin_amdgcn_cvt_pk_fp8_f32(acc[12], acc[13], v, false);
  v = __builtin_amdgcn_cvt_pk_fp8_f32(acc[14], acc[15], v, true);
  o.w = v;
  return o;
}

// ---------- FRONT: blocks [0,A2B) = per-chunk 256-bucket histogram;
//                   blocks [A2B,..) = gemm1 (4 threads/node, W1 in LDS) ----------
__global__ __launch_bounds__(256) void k_front(const void* __restrict__ idx,
                                               unsigned* __restrict__ histT,
                                               long E, int chunk, unsigned M,
                                               const float* __restrict__ X,
                                               const float* __restrict__ W1,
                                               unsigned char* __restrict__ h, int n) {
  __shared__ float smem[2048];   // hist uses 1 KB as uint; gemm1 uses 8 KB as W tile
  const int t = threadIdx.x;
  if (blockIdx.x < A2B) {
    unsigned* cnt = (unsigned*)smem;
    const int b = blockIdx.x;
    const int is64 = detect_is64(idx);
    cnt[t] = 0;
    __syncthreads();
    const long e0 = (long)b * chunk;
    long e1 = e0 + chunk; if (e1 > E) e1 = E;
    for (long e = e0 + t; e < e1; e += 256) {
      unsigned d = (unsigned)ld_idx(idx, E + e, is64);
      atomicAdd(&cnt[__umulhi(d, M)], 1u);
    }
    __syncthreads();
    histT[(size_t)t * A2B + b] = cnt[t];   // k-major
    return;
  }
  // ----- gemm1 -----
  float* Ws = smem;
  for (int i = t; i < 2048; i += 256)
    ((float4*)Ws)[i] = ((const float4*)W1)[i];
  __syncthreads();
  int gid = (blockIdx.x - A2B) * 256 + t;
  int node = gid >> 2;
  int fg = (gid & 3) * 16;
  if (node >= n) return;
  const float4* xr4 = (const float4*)(X + (size_t)node * 128);
  float acc[16];
#pragma unroll
  for (int f = 0; f < 16; ++f) acc[f] = 0.0f;
  for (int k4 = 0; k4 < 32; ++k4) {
    float4 x = xr4[k4];
#pragma unroll
    for (int kk = 0; kk < 4; ++kk) {
      float xv = (kk == 0) ? x.x : (kk == 1) ? x.y : (kk == 2) ? x.z : x.w;
      const float4* wrow = (const float4*)(Ws + (k4 * 4 + kk) * 64 + fg);
#pragma unroll
      for (int f4 = 0; f4 < 4; ++f4) {
        float4 w = wrow[f4];
        acc[f4 * 4 + 0] = fmaf(xv, w.x, acc[f4 * 4 + 0]);
        acc[f4 * 4 + 1] = fmaf(xv, w.y, acc[f4 * 4 + 1]);
        acc[f4 * 4 + 2] = fmaf(xv, w.z, acc[f4 * 4 + 2]);
        acc[f4 * 4 + 3] = fmaf(xv, w.w, acc[f4 * 4 + 3]);
      }
    }
  }
  *(uint4*)(h + (size_t)node * 64 + fg) = pack16_fp8(acc);
}

// ---------- C1: per-bucket column scan (256 blocks, coalesced) ----------
__global__ __launch_bounds__(256) void k_colscan(const unsigned* __restrict__ histT,
                                                 unsigned* __restrict__ baseT,
                                                 unsigned* __restrict__ colsum) {
  __shared__ unsigned sh[256];
  const int k = blockIdx.x, t = threadIdx.x;
  const uint2 v = ((const uint2*)(histT + (size_t)k * A2B))[t];
  unsigned s = v.x + v.y;
  sh[t] = s;
  __syncthreads();
  for (int off = 1; off < 256; off <<= 1) {
    unsigned u = (t >= off) ? sh[t - off] : 0;
    __syncthreads();
    sh[t] += u;
    __syncthreads();
  }
  unsigned excl = sh[t] - s;
  uint2 o; o.x = excl; o.y = excl + v.x;
  ((uint2*)(baseT + (size_t)k * A2B))[t] = o;
  if (t == 255) colsum[k] = sh[255];
}

// ---------- A2: LDS counting-sort each chunk by bucket, write bucket-major packed recs ----------
__global__ __launch_bounds__(A2T) void k_bucket(const void* __restrict__ idx,
                                                const float* __restrict__ w,
                                                const unsigned* __restrict__ baseT,
                                                const unsigned* __restrict__ colsum,
                                                uint2* __restrict__ recs,
                                                long E, int chunk, unsigned M) {
  __shared__ uint2 stage[STG];                      // 25.6 KB
  __shared__ unsigned cnt[256], lofs[256], lbase[256], bcol[256], scanb[256];
  const int b = blockIdx.x, t = threadIdx.x;
  const long e0 = (long)b * chunk;
  long e1 = e0 + chunk; if (e1 > E) e1 = E;
  const int m = (int)(e1 - e0);
  const int is64 = detect_is64(idx);
  if (t < 256) scanb[t] = colsum[t];
  __syncthreads();
  for (int off = 1; off < 256; off <<= 1) {
    unsigned u = 0;
    if (t < 256 && t >= off) u = scanb[t - off];
    __syncthreads();
    if (t < 256) scanb[t] += u;
    __syncthreads();
  }
  if (t < 256) {
    bcol[t] = (scanb[t] - colsum[t]) + baseT[(size_t)t * A2B + b];
    cnt[t] = 0;
  }
  __syncthreads();
  unsigned short dc[8]; unsigned char kc[8];
  int nk = 0;
  for (long e = e0 + t; e < e1; e += A2T, ++nk) {
    unsigned d = (unsigned)ld_idx(idx, E + e, is64);
    unsigned kb = __umulhi(d, M);
    dc[nk] = (unsigned short)d; kc[nk] = (unsigned char)kb;
    atomicAdd(&cnt[kb], 1u);
  }
  __syncthreads();
  if (t < 256) scanb[t] = cnt[t];
  __syncthreads();
  for (int off = 1; off < 256; off <<= 1) {
    unsigned u = 0;
    if (t < 256 && t >= off) u = scanb[t - off];
    __syncthreads();
    if (t < 256) scanb[t] += u;
    __syncthreads();
  }
  if (t < 256) { unsigned ex = scanb[t] - cnt[t]; lbase[t] = ex; lofs[t] = ex; }
  __syncthreads();
  nk = 0;
  for (long e = e0 + t; e < e1; e += A2T, ++nk) {
    unsigned s = (unsigned)ld_idx(idx, e, is64);
    float wv = w[e];
    unsigned kb = kc[nk];
    unsigned pos = atomicAdd(&lofs[kb], 1u);
    stage[pos] = make_uint2(s | ((unsigned)dc[nk] << 16), __float_as_uint(wv));
  }
  __syncthreads();
  for (int i = t; i < m; i += A2T) {
    uint2 r = stage[i];
    unsigned kb = __umulhi(r.x >> 16, M);
    recs[bcol[kb] + (unsigned)i - lbase[kb]] = r;
  }
}

// ---------- B: one block per bucket; pass-1 only: rowptr + dis ----------
__global__ __launch_bounds__(1024) void k_build(const uint2* __restrict__ recs,
                                                const unsigned* __restrict__ colsum,
                                                int* __restrict__ rowptr,
                                                float* __restrict__ dis,
                                                int n, int dwidth, long E) {
  __shared__ float wsum[256];
  __shared__ unsigned cnt[256], scanb[256];
  __shared__ int shr0, shr1;
  const int k = blockIdx.x, t = threadIdx.x;
  const int d0 = k * dwidth;
  if (t < 256) scanb[t] = colsum[t];
  __syncthreads();
  for (int off = 1; off < 256; off <<= 1) {
    unsigned u = 0;
    if (t < 256 && t >= off) u = scanb[t - off];
    __syncthreads();
    if (t < 256) scanb[t] += u;
    __syncthreads();
  }
  if (t == k) { shr1 = (int)scanb[t]; shr0 = (int)(scanb[t] - colsum[t]); }
  if (t < 256) { wsum[t] = 0.0f; cnt[t] = 0; }
  __syncthreads();
  const int r0 = shr0, r1 = shr1;
  const int m = r1 - r0;
  for (int i = t; i < m; i += 1024) {
    uint2 r = recs[r0 + i];
    int dl = (int)(r.x >> 16) - d0;
    atomicAdd(&cnt[dl], 1u);
    atomicAdd(&wsum[dl], __uint_as_float(r.y));
  }
  __syncthreads();
  if (t < 256) scanb[t] = cnt[t];
  __syncthreads();
  for (int off = 1; off < 256; off <<= 1) {
    unsigned u = 0;
    if (t < 256 && t >= off) u = scanb[t - off];
    __syncthreads();
    if (t < 256) scanb[t] += u;
    __syncthreads();
  }
  if (t < 256) {
    unsigned ex = scanb[t] - cnt[t];
    int d = d0 + t;
    if (t < dwidth && d < n) {
      rowptr[d] = r0 + (int)ex;
      dis[d] = rsqrtf(1.0f + wsum[t]);   // deg >= 1 (self-loop weight 1)
    }
  }
  if (k == gridDim.x - 1 && t == 0) rowptr[n] = (int)E;
}

// ---------- P: CSR scatter with dis[src] folded into the weight ----------
// Runs after k_build (dis fully written). lofs re-seeds from rowptr.
__global__ __launch_bounds__(1024) void k_place(const uint2* __restrict__ recs,
                                                const unsigned* __restrict__ colsum,
                                                const int* __restrict__ rowptr,
                                                const float* __restrict__ dis,
                                                float2* __restrict__ edges,
                                                int n, int dwidth) {
  __shared__ unsigned lofs[256], scanb[256];
  __shared__ int shr0, shr1;
  const int k = blockIdx.x, t = threadIdx.x;
  const int d0 = k * dwidth;
  if (t < 256) scanb[t] = colsum[t];
  __syncthreads();
  for (int off = 1; off < 256; off <<= 1) {
    unsigned u = 0;
    if (t < 256 && t >= off) u = scanb[t - off];
    __syncthreads();
    if (t < 256) scanb[t] += u;
    __syncthreads();
  }
  if (t == k) { shr1 = (int)scanb[t]; shr0 = (int)(scanb[t] - colsum[t]); }
  if (t < 256) {
    int d = d0 + t;
    lofs[t] = (t < dwidth && d < n) ? (unsigned)rowptr[d] : 0u;
  }
  __syncthreads();
  const int r0 = shr0, r1 = shr1;
  const int m = r1 - r0;
  for (int i = t; i < m; i += 1024) {
    uint2 r = recs[r0 + i];
    unsigned src = r.x & 0xffffu;
    float wn = __uint_as_float(r.y) * dis[src];
    unsigned pos = atomicAdd(&lofs[(int)(r.x >> 16) - d0], 1u);
    edges[pos] = make_float2(__uint_as_float(src), wn);
  }
}

// ---------- gather core: aggregate one node's neighborhood (2 nodes/wave) ----------
// 12-slot window (48 edges >= deg for ~99.8% of nodes): ALL rec loads issue,
// then ALL h-row loads, then the FMA block. 8 feature-lanes share each rec
// address (HW broadcast); tail slots clamp to end-1 and zero the weight.
// Weight already carries dis[src] (k_place).
__device__ __forceinline__ void gather_acc(const unsigned char* __restrict__ h,
                                           const float2* __restrict__ edges,
                                           int beg, int end, int eg, int fl,
                                           float* acc) {
  f32x2 a0 = {0.0f, 0.0f}, a1 = {0.0f, 0.0f}, a2 = {0.0f, 0.0f}, a3 = {0.0f, 0.0f};
  const unsigned char* hf = h + fl * 8;
  for (int base = beg; base < end; base += 48) {
    float2 rv[12];
#pragma unroll
    for (int s = 0; s < 12; ++s) {
      int idx = base + s * 4 + eg;
      rv[s] = edges[min(idx, end - 1)];
    }
    uint2 hv[12];
#pragma unroll
    for (int s = 0; s < 12; ++s)
      hv[s] = *(const uint2*)(hf + (size_t)__float_as_int(rv[s].x) * 64);
#pragma unroll
    for (int s = 0; s < 12; ++s) {
      float w = (base + s * 4 + eg < end) ? rv[s].y : 0.0f;
      f32x2 nj2 = {w, w};
      a0 += __builtin_amdgcn_cvt_pk_f32_fp8(hv[s].x, false) * nj2;
      a1 += __builtin_amdgcn_cvt_pk_f32_fp8(hv[s].x, true)  * nj2;
      a2 += __builtin_amdgcn_cvt_pk_f32_fp8(hv[s].y, false) * nj2;
      a3 += __builtin_amdgcn_cvt_pk_f32_fp8(hv[s].y, true)  * nj2;
    }
  }
  acc[0] = a0[0]; acc[1] = a0[1]; acc[2] = a1[0]; acc[3] = a1[1];
  acc[4] = a2[0]; acc[5] = a2[1]; acc[6] = a3[0]; acc[7] = a3[1];
#pragma unroll
  for (int off = 8; off < 32; off <<= 1)
#pragma unroll
    for (int i = 0; i < 8; ++i) acc[i] += __shfl_xor(acc[i], off);
}

// epilogue helper: acc += b + h_self * s0^2
__device__ __forceinline__ void add_bias_self(const unsigned char* __restrict__ h,
                                              const float* __restrict__ b,
                                              int node, int fl, float s0, float* acc) {
  uint2 hv = *(const uint2*)(h + (size_t)node * 64 + fl * 8);
  f32x2 q0 = __builtin_amdgcn_cvt_pk_f32_fp8(hv.x, false);
  f32x2 q1 = __builtin_amdgcn_cvt_pk_f32_fp8(hv.x, true);
  f32x2 q2 = __builtin_amdgcn_cvt_pk_f32_fp8(hv.y, false);
  f32x2 q3 = __builtin_amdgcn_cvt_pk_f32_fp8(hv.y, true);
  float hs[8] = {q0[0], q0[1], q1[0], q1[1], q2[0], q2[1], q3[0], q3[1]};
  float4 bv0 = *(const float4*)(b + fl * 8);
  float4 bv1 = *(const float4*)(b + fl * 8 + 4);
  float bb[8] = {bv0.x, bv0.y, bv0.z, bv0.w, bv1.x, bv1.y, bv1.z, bv1.w};
  float s2 = s0 * s0;
#pragma unroll
  for (int i = 0; i < 8; ++i) acc[i] += bb[i] + hs[i] * s2;
}

// ---------- MID: gather layer-1 + fused gemm2 -> layer-2 h (fp8) ----------
__global__ __launch_bounds__(256) void k_gather_mid(const unsigned char* __restrict__ h,
                                                    const float* __restrict__ dis,
                                                    const float2* __restrict__ edges,
                                                    const int* __restrict__ rowptr,
                                                    const float* __restrict__ b1,
                                                    const float* __restrict__ W2,
                                                    unsigned char* __restrict__ h2,
                                                    int n, int GP) {
  __shared__ float W2s[64 * 64];   // 16 KB
  __shared__ float xs[8 * 64];     // 2 KB: relu'd layer-1 output for this block's 8 nodes
  const int t = threadIdx.x;
  for (int i = t; i < 1024; i += 256)
    ((float4*)W2s)[i] = ((const float4*)W2)[i];
  int lane = t & 63;
  int l32 = lane & 31;
  int fl = lane & 7;
  int eg = (lane >> 3) & 3;
  int nl = t >> 5;                       // node-local 0..7
  const int g = swz_group(blockIdx.x, GP);
  int node = g * 8 + nl;
  int beg = 0, end = 0; float s0 = 0.0f;
  if (node < n) { beg = rowptr[node]; end = rowptr[node + 1]; s0 = dis[node]; }
  float acc[8];
  gather_acc(h, edges, beg, end, eg, fl, acc);
  if (node < n) {
#pragma unroll
    for (int i = 0; i < 8; ++i) acc[i] *= s0;
    add_bias_self(h, b1, node, fl, s0, acc);
    if (eg == 0) {
#pragma unroll
      for (int i = 0; i < 8; ++i) xs[nl * 64 + fl * 8 + i] = fmaxf(acc[i], 0.0f);
    }
  }
  __syncthreads();
  // gemm2: thread t computes outputs f=2*tl, 2*tl+1 for node-local nl
  int tl = l32;  // t>>5 == nl, t&31 within node
  int node2 = g * 8 + (t >> 5);
  if (node2 >= n) return;
  const float* xrow = xs + (t >> 5) * 64;
  int f = tl * 2;
  float a0 = 0.0f, a1 = 0.0f;
#pragma unroll 8
  for (int k = 0; k < 64; ++k) {
    float xk = xrow[k];
    f32x2 wv = *(const f32x2*)(W2s + k * 64 + f);
    a0 = fmaf(xk, wv[0], a0);
    a1 = fmaf(xk, wv[1], a1);
  }
  unsigned v = __builtin_amdgcn_cvt_pk_fp8_f32(a0, a1, 0u, false);
  *(unsigned short*)(h2 + (size_t)node2 * 64 + f) = (unsigned short)v;
}

// ---------- FIN: gather layer-2 + readout (sigmoid(relu(z) . Wl + bl)) ----------
__global__ __launch_bounds__(256) void k_gather_fin(const unsigned char* __restrict__ h,
                                                    const float* __restrict__ dis,
                                                    const float2* __restrict__ edges,
                                                    const int* __restrict__ rowptr,
                                                    const float* __restrict__ b2,
                                                    const float* __restrict__ Wl,
                                                    const float* __restrict__ bl,
                                                    float* __restrict__ out,
                                                    int n, int GP) {
  int lane = threadIdx.x & 63;
  int l32 = lane & 31;
  int fl = lane & 7;
  int eg = (lane >> 3) & 3;
  const int g = swz_group(blockIdx.x, GP);
  int node = g * 8 + (int)(threadIdx.x >> 5);
  if (node >= n) return;
  int beg = rowptr[node], end = rowptr[node + 1];
  float s0 = dis[node];
  float acc[8];
  gather_acc(h, edges, beg, end, eg, fl, acc);
#pragma unroll
  for (int i = 0; i < 8; ++i) acc[i] *= s0;
  add_bias_self(h, b2, node, fl, s0, acc);
  float4 wl0 = *(const float4*)(Wl + fl * 8);
  float4 wl1 = *(const float4*)(Wl + fl * 8 + 4);
  float wl[8] = {wl0.x, wl0.y, wl0.z, wl0.w, wl1.x, wl1.y, wl1.z, wl1.w};
  float v = 0.0f;
#pragma unroll
  for (int i = 0; i < 8; ++i) v += fmaxf(acc[i], 0.0f) * wl[i];
#pragma unroll
  for (int off = 1; off < 8; off <<= 1) v += __shfl_xor(v, off);
  if (l32 == 0) out[node] = 1.0f / (1.0f + expf(-(v + bl[0])));
}

extern "C" void kernel_launch(void* const* d_in, const int* in_sizes, int n_in,
                              void* d_out, int out_size, void* d_ws, size_t ws_size,
                              hipStream_t stream) {
  const float* X  = (const float*)d_in[0];
  const void*  EI = d_in[1];
  const float* EW = (const float*)d_in[2];
  const float* W1 = (const float*)d_in[3];
  const float* b1 = (const float*)d_in[4];
  const float* W2 = (const float*)d_in[5];
  const float* b2 = (const float*)d_in[6];
  const float* Wl = (const float*)d_in[7];
  const float* bl = (const float*)d_in[8];
  float* out = (float*)d_out;

  const int  n = in_sizes[0] / 128;      // 50000 (must be <= 65536 for packed recs)
  const long E = (long)in_sizes[1] / 2;  // 1,600,000

  const int chunk  = (int)((E + A2B - 1) / A2B);       // 3125 (<= STG)
  // dwidth: nodes per bucket, rounded to a multiple of 8 (196 -> 200) so each
  // bucket holds exactly GP = dwidth/8 node-groups for the XCD swizzle.
  const int dwidth = (((n + 255) / 256) + 7) & ~7;     // 200 (<= 256)
  const int GP     = dwidth >> 3;                      // 25 groups/bucket
  const unsigned M = (unsigned)((0x100000000ULL + (unsigned)dwidth - 1) / (unsigned)dwidth);

  auto align = [](size_t x) { return (x + 255) & ~(size_t)255; };
  char* ws = (char*)d_ws;
  size_t off = 0;
  float*         dis    = (float*)(ws + off);         off += align((size_t)n * 4);
  int*           rowptr = (int*)(ws + off);           off += align((size_t)(n + 1) * 4);
  unsigned*      colsum = (unsigned*)(ws + off);      off += align(256 * 4);
  unsigned*      histT  = (unsigned*)(ws + off);      off += align((size_t)A2B * 256 * 4);
  unsigned*      baseT  = (unsigned*)(ws + off);      off += align((size_t)A2B * 256 * 4);
  uint2*         recs   = (uint2*)(ws + off);         off += align((size_t)E * 8);
  float2*        edges  = (float2*)(ws + off);        off += align((size_t)E * 8);
  unsigned char* A      = (unsigned char*)(ws + off); off += align((size_t)n * 64);
  unsigned char* A2     = (unsigned char*)(ws + off); off += align((size_t)n * 64);

  const int nbW = 32 * dwidth;          // gather blocks: 256 buckets * GP groups
  const int nbG = (n * 4 + 255) / 256;  // gemm1 blocks (4 threads/node)

  k_front<<<A2B + nbG, dim3(256), 0, stream>>>(EI, histT, E, chunk, M, X, W1, A, n);
  k_colscan<<<256, 256, 0, stream>>>(histT, baseT, colsum);
  k_bucket<<<A2B, A2T, 0, stream>>>(EI, EW, baseT, colsum, recs, E, chunk, M);
  k_build<<<256, 1024, 0, stream>>>(recs, colsum, rowptr, dis, n, dwidth, E);
  k_place<<<256, 1024, 0, stream>>>(recs, colsum, rowptr, dis, edges, n, dwidth);

  // layer 1 gather + fused layer-2 GEMM
  k_gather_mid<<<nbW, dim3(256), 0, stream>>>(A, dis, edges, rowptr, b1, W2, A2, n, GP);
  // layer 2 gather + fused readout
  k_gather_fin<<<nbW, dim3(256), 0, stream>>>(A2, dis, edges, rowptr, b2, Wl, bl, out, n, GP);
}